// Round 8
// baseline (550.321 us; speedup 1.0000x reference)
//
#include <hip/hip_runtime.h>
#include <hip/hip_bf16.h>

// Problem constants (from reference): b=2,h=8 -> BH=16; t=s=384; d=64.
#define BH 16
#define NT 384
#define NS 384
#define DD 64

static constexpr float TWO_LOG2E = 2.8853900817779268f; // 2*log2(e)
static constexpr float LOG2E     = 1.4426950408889634f;

// Static scratch: Ea = exp(2*qp), Eb = exp(2*kp). 2 x 1.5 MB, 16B aligned.
__device__ float4 g_Ea4[(size_t)BH * NT * DD / 4];
__device__ float4 g_Eb4[(size_t)BH * NS * DD / 4];

// ---------------------------------------------------------------------------
// K1: proj + exp. Block owns 32 rows of one tensor (q or k). x-tile staged in
// LDS; W row per lane in VGPRs; x read back as uniform LDS b128 broadcasts.
// ---------------------------------------------------------------------------
__global__ __launch_bounds__(256) void k1_proj(
    const float* __restrict__ q, const float* __restrict__ k,
    const float* __restrict__ Wq, const float* __restrict__ Wk)
{
    __shared__ float xt[32 * 64]; // 8KB
    const int bid    = blockIdx.x;       // [0, 384)
    const int tensor = bid / 192;        // 0=q, 1=k
    const int tile   = bid % 192;        // 32-row tiles over 6144 rows
    const int tid  = threadIdx.x;
    const int lane = tid & 63;
    const int w    = tid >> 6;

    const float* __restrict__ X = tensor ? k  : q;
    const float* __restrict__ W = tensor ? Wk : Wq;
    float* __restrict__ E = tensor ? (float*)g_Eb4 : (float*)g_Ea4;

    const size_t base = (size_t)tile * 32;

    {
        const float4* __restrict__ src =
            reinterpret_cast<const float4*>(X + base * 64);
        float4* dst = reinterpret_cast<float4*>(xt);
#pragma unroll
        for (int i = 0; i < 2; ++i) dst[tid + i * 256] = src[tid + i * 256];
    }

    float wr[64];
    {
        const float* wrow = W + lane * 64;
#pragma unroll
        for (int i = 0; i < 64; i += 4) {
            float4 v = *reinterpret_cast<const float4*>(wrow + i);
            wr[i] = v.x; wr[i + 1] = v.y; wr[i + 2] = v.z; wr[i + 3] = v.w;
        }
    }
    __syncthreads();

#pragma unroll
    for (int r8 = 0; r8 < 8; ++r8) {
        const int r = w * 8 + r8;
        float a0 = 0.f, a1 = 0.f, a2 = 0.f, a3 = 0.f;
#pragma unroll
        for (int d4 = 0; d4 < 16; ++d4) {
            const float4 xv = *reinterpret_cast<const float4*>(&xt[r * 64 + d4 * 4]);
            a0 = fmaf(xv.x, wr[d4 * 4 + 0], a0);
            a1 = fmaf(xv.y, wr[d4 * 4 + 1], a1);
            a2 = fmaf(xv.z, wr[d4 * 4 + 2], a2);
            a3 = fmaf(xv.w, wr[d4 * 4 + 3], a3);
        }
        const float dot = (a0 + a1) + (a2 + a3);
        E[(base + r) * 64 + lane] = __builtin_amdgcn_exp2f(TWO_LOG2E * dot);
    }
}

// ---------------------------------------------------------------------------
// K2 fused v3: scores + softmax + PV, block = (bh, 12 t-rows), 6 waves.
// Phase A operand delivery fixed vs v2:
//   * Ea tile staged in LDS (3KB); inner loop reads uniform ds_read_b128
//     broadcasts (conflict-free) — no global loads in the loop.
//   * v_w stream eliminated algebraically: vv/(1+ea*eb) = c/(ea+u) with
//     per-lane u[e]=rcp(eb[e]), c[e]=vv[e]*u[e]. u,c are COMPUTED values ->
//     compiler must keep them in VGPRs (128 regs), cannot refold to loads.
//   * inner loop = v_add + v_rcp + v_fma per element.
// Softmax: max-free (|score| < 24, exp2 safe in fp32), butterfly chunk sums +
// tiny LDS combine; single write of P to LDS + global attn.
// PV: V chunk staged [64][68]; lane = (s-subgroup g, d-quad dq); b128 V reads;
// P read as uniform b32 broadcast; shfl_xor(16,32) reduce; g==0 writes out.
// Grid 512 (16 bh x 32 tiles) = 2 blocks/CU, 12 waves/CU.
// ---------------------------------------------------------------------------
__global__ __launch_bounds__(384, 3) void k2_fused(
    const float* __restrict__ v_w, const float* __restrict__ V,
    float* __restrict__ out, float* __restrict__ attn)
{
    __shared__ float eal[12 * 64];   // 3KB staged Ea tile
    __shared__ float Pl[12 * 388];   // 18.6KB normalized attention tile
    __shared__ float Vt[64 * 68];    // 17.4KB V chunk
    __shared__ float ssum[12 * 8];   // per-row per-wave chunk sums

    const int bid  = blockIdx.x;     // [0, 512)
    const int bh   = bid >> 5;
    const int t0   = (bid & 31) * 12;
    const int tid  = threadIdx.x;
    const int lane = tid & 63;
    const int wv   = __builtin_amdgcn_readfirstlane(tid >> 6); // 0..5

    // stage Ea tile: 768 floats = 192 float4
    if (tid < 192) {
        const float4* __restrict__ src = reinterpret_cast<const float4*>(
            (const float*)g_Ea4 + ((size_t)bh * NT + t0) * 64);
        reinterpret_cast<float4*>(eal)[tid] = src[tid];
    }

    // per-lane setup: u[e] = 1/eb[e], c[e] = vv[e]*u[e]; C0 = sum(vv)
    float u[64], c[64];
    float C0;
    {
        const float* __restrict__ ebp =
            (const float*)g_Eb4 + ((size_t)bh * NS + wv * 64 + lane) * 64;
#pragma unroll
        for (int i = 0; i < 16; ++i) {
            const float4 v = *reinterpret_cast<const float4*>(ebp + i * 4);
            u[i * 4 + 0] = __builtin_amdgcn_rcpf(v.x);
            u[i * 4 + 1] = __builtin_amdgcn_rcpf(v.y);
            u[i * 4 + 2] = __builtin_amdgcn_rcpf(v.z);
            u[i * 4 + 3] = __builtin_amdgcn_rcpf(v.w);
        }
        const float vvl = v_w[lane]; // one coalesced load
        float s = vvl;
#pragma unroll
        for (int o = 32; o > 0; o >>= 1) s += __shfl_xor(s, o, 64);
        C0 = s;
#pragma unroll
        for (int e = 0; e < 64; ++e) c[e] = __shfl(vvl, e, 64) * u[e];
    }
    __syncthreads();

    // ---------------- Phase A: raw scores (uniform LDS + per-lane regs) ----
    float p[12];
#pragma unroll
    for (int r = 0; r < 12; ++r) {
        const float* __restrict__ ear = &eal[r * 64];
        float a0 = 0.f, a1 = 0.f, a2 = 0.f, a3 = 0.f;
#pragma unroll
        for (int e = 0; e < 64; e += 4) {
            const float4 A = *reinterpret_cast<const float4*>(&ear[e]);
            a0 = fmaf(c[e + 0], __builtin_amdgcn_rcpf(A.x + u[e + 0]), a0);
            a1 = fmaf(c[e + 1], __builtin_amdgcn_rcpf(A.y + u[e + 1]), a1);
            a2 = fmaf(c[e + 2], __builtin_amdgcn_rcpf(A.z + u[e + 2]), a2);
            a3 = fmaf(c[e + 3], __builtin_amdgcn_rcpf(A.w + u[e + 3]), a3);
        }
        p[r] = C0 - 2.f * ((a0 + a1) + (a2 + a3));
    }

    // ---------------- Softmax (max-free; scores bounded ±24) ----------------
#pragma unroll
    for (int r = 0; r < 12; ++r) {
        p[r] = __builtin_amdgcn_exp2f(p[r] * LOG2E);
        float s = p[r];
#pragma unroll
        for (int o = 32; o > 0; o >>= 1) s += __shfl_xor(s, o, 64);
        if (lane == 0) ssum[r * 8 + wv] = s;
    }
    __syncthreads();

#pragma unroll
    for (int r = 0; r < 12; ++r) {
        const float tot = ((ssum[r * 8 + 0] + ssum[r * 8 + 1]) +
                           (ssum[r * 8 + 2] + ssum[r * 8 + 3])) +
                          (ssum[r * 8 + 4] + ssum[r * 8 + 5]);
        p[r] *= __builtin_amdgcn_rcpf(tot);
        Pl[r * 388 + wv * 64 + lane] = p[r];
        attn[((size_t)bh * NT + t0 + r) * NS + wv * 64 + lane] = p[r];
    }

    // ---------------- PV: out[r][d] = sum_s P[r][s] V[s][d] ----------------
    const int g  = lane >> 4;        // s-subgroup 0..3
    const int dq = (lane & 15) * 4;  // d-quad
    const int r0 = 2 * wv, r1 = 2 * wv + 1;
    float4 O0 = {0.f, 0.f, 0.f, 0.f};
    float4 O1 = {0.f, 0.f, 0.f, 0.f};
    const float4* __restrict__ Vg =
        reinterpret_cast<const float4*>(V + (size_t)bh * NS * 64);

    for (int sc = 0; sc < 6; ++sc) {
        __syncthreads(); // Pl written (sc==0) / previous chunk consumed
        for (int j = tid; j < 1024; j += 384) {
            const float4 v = Vg[sc * 1024 + j];
            const int row = j >> 4;
            const int c4  = j & 15;
            *reinterpret_cast<float4*>(&Vt[row * 68 + c4 * 4]) = v;
        }
        __syncthreads();

        const float* __restrict__ P0 = &Pl[r0 * 388 + sc * 64];
        const float* __restrict__ P1 = &Pl[r1 * 388 + sc * 64];
#pragma unroll
        for (int s4 = 0; s4 < 16; ++s4) {
            const int sl = s4 * 4 + g;
            const float4 v4 = *reinterpret_cast<const float4*>(&Vt[sl * 68 + dq]);
            const float q0 = P0[sl];
            const float q1 = P1[sl];
            O0.x = fmaf(q0, v4.x, O0.x); O0.y = fmaf(q0, v4.y, O0.y);
            O0.z = fmaf(q0, v4.z, O0.z); O0.w = fmaf(q0, v4.w, O0.w);
            O1.x = fmaf(q1, v4.x, O1.x); O1.y = fmaf(q1, v4.y, O1.y);
            O1.z = fmaf(q1, v4.z, O1.z); O1.w = fmaf(q1, v4.w, O1.w);
        }
    }

    // reduce across the 4 s-subgroups (lane bits 4,5)
#pragma unroll
    for (int o = 16; o <= 32; o <<= 1) {
        O0.x += __shfl_xor(O0.x, o, 64); O0.y += __shfl_xor(O0.y, o, 64);
        O0.z += __shfl_xor(O0.z, o, 64); O0.w += __shfl_xor(O0.w, o, 64);
        O1.x += __shfl_xor(O1.x, o, 64); O1.y += __shfl_xor(O1.y, o, 64);
        O1.z += __shfl_xor(O1.z, o, 64); O1.w += __shfl_xor(O1.w, o, 64);
    }
    if (g == 0) {
        float* __restrict__ op = out + ((size_t)bh * NT + t0 + r0) * 64 + dq;
        *reinterpret_cast<float4*>(op)      = O0;
        *reinterpret_cast<float4*>(op + 64) = O1;
    }
}

extern "C" void kernel_launch(void* const* d_in, const int* in_sizes, int n_in,
                              void* d_out, int out_size, void* d_ws, size_t ws_size,
                              hipStream_t stream) {
    const float* q  = (const float*)d_in[0];
    const float* k  = (const float*)d_in[1];
    const float* v  = (const float*)d_in[2];
    const float* Wq = (const float*)d_in[3];
    const float* Wk = (const float*)d_in[4];
    const float* vw = (const float*)d_in[5];

    float* out  = (float*)d_out;              // (b,h,t,d) = 393216
    float* attn = out + (size_t)BH * NT * DD; // (b,h,t,s) = 2359296

    k1_proj <<<384, 256, 0, stream>>>(q, k, Wq, Wk);
    k2_fused<<<512, 384, 0, stream>>>(vw, v, out, attn);
}

// Round 13
// 121.721 us; speedup vs baseline: 4.5212x; 4.5212x over previous
//
#include <hip/hip_runtime.h>
#include <hip/hip_bf16.h>

// Problem constants (from reference): b=2,h=8 -> BH=16; t=s=384; d=64.
#define BH 16
#define NT 384
#define NS 384
#define DD 64

static constexpr float TWO_LOG2E = 2.8853900817779268f; // 2*log2(e)
static constexpr float LOG2E     = 1.4426950408889634f;

// Static scratch: Ea = exp(2*qp), Eb = exp(2*kp). 2 x 1.5 MB, 16B aligned.
__device__ float4 g_Ea4[(size_t)BH * NT * DD / 4];
__device__ float4 g_Eb4[(size_t)BH * NS * DD / 4];

// ---------------------------------------------------------------------------
// K1: proj + exp. Block owns 32 rows of one tensor (q or k). x-tile staged in
// LDS; W row per lane in VGPRs; x read back as uniform LDS b128 broadcasts.
// ---------------------------------------------------------------------------
__global__ __launch_bounds__(256) void k1_proj(
    const float* __restrict__ q, const float* __restrict__ k,
    const float* __restrict__ Wq, const float* __restrict__ Wk)
{
    __shared__ float xt[32 * 64]; // 8KB
    const int bid    = blockIdx.x;       // [0, 384)
    const int tensor = bid / 192;        // 0=q, 1=k
    const int tile   = bid % 192;        // 32-row tiles over 6144 rows
    const int tid  = threadIdx.x;
    const int lane = tid & 63;
    const int w    = tid >> 6;

    const float* __restrict__ X = tensor ? k  : q;
    const float* __restrict__ W = tensor ? Wk : Wq;
    float* __restrict__ E = tensor ? (float*)g_Eb4 : (float*)g_Ea4;

    const size_t base = (size_t)tile * 32;

    {
        const float4* __restrict__ src =
            reinterpret_cast<const float4*>(X + base * 64);
        float4* dst = reinterpret_cast<float4*>(xt);
#pragma unroll
        for (int i = 0; i < 2; ++i) dst[tid + i * 256] = src[tid + i * 256];
    }

    float wr[64];
    {
        const float* wrow = W + lane * 64;
#pragma unroll
        for (int i = 0; i < 64; i += 4) {
            float4 v = *reinterpret_cast<const float4*>(wrow + i);
            wr[i] = v.x; wr[i + 1] = v.y; wr[i + 2] = v.z; wr[i + 3] = v.w;
        }
    }
    __syncthreads();

#pragma unroll
    for (int r8 = 0; r8 < 8; ++r8) {
        const int r = w * 8 + r8;
        float a0 = 0.f, a1 = 0.f, a2 = 0.f, a3 = 0.f;
#pragma unroll
        for (int d4 = 0; d4 < 16; ++d4) {
            const float4 xv = *reinterpret_cast<const float4*>(&xt[r * 64 + d4 * 4]);
            a0 = fmaf(xv.x, wr[d4 * 4 + 0], a0);
            a1 = fmaf(xv.y, wr[d4 * 4 + 1], a1);
            a2 = fmaf(xv.z, wr[d4 * 4 + 2], a2);
            a3 = fmaf(xv.w, wr[d4 * 4 + 3], a3);
        }
        const float dot = (a0 + a1) + (a2 + a3);
        E[(base + r) * 64 + lane] = __builtin_amdgcn_exp2f(TWO_LOG2E * dot);
    }
}

// ---------------------------------------------------------------------------
// K2 fused v4: block = (bh, 12 t-rows), 384 threads = 6 waves. All waves walk
// the 6 s-chunks TOGETHER; per chunk the block stages Eb[64][68] in LDS
// (coalesced), each lane hoists its row to eb[64] VGPRs (proven idiom from
// r1/r5: LDS-sourced hoists stay in registers), and wave wv computes its 2
// t-rows (2wv, 2wv+1) with lane<->s. Ea tile + v_w read as uniform LDS b128
// broadcasts (conflict-free). Inner loop: fma + rcp + fma per element, zero
// global/scratch traffic. Each t-row is wave-owned -> softmax is in-register
// (max-free, |score|<24): 12 exp2 + 2 butterflies, write attn once. PV reads
// V chunk from the same LDS buffer (b128, 16-lane-contiguous) with P
// broadcast via shfl from regs; shfl_xor(16,32) reduce; g==0 writes out.
// All sc-loops #pragma unroll'd => p0/p1 statically indexed (no scratch).
// No min-wave launch bound: ~115 VGPRs, no spill pressure.
// Grid 512 (16 bh x 32 tiles).
// ---------------------------------------------------------------------------
__global__ __launch_bounds__(384) void k2_fused(
    const float* __restrict__ v_w, const float* __restrict__ V,
    float* __restrict__ out, float* __restrict__ attn)
{
    __shared__ float eal[12 * 64];  // 3KB   Ea tile (uniform-broadcast reads)
    __shared__ float vwl[64];       // 256B  v_w     (uniform-broadcast reads)
    __shared__ float ebl[64 * 68];  // 17.4KB Eb chunk; reused as V tile in PV

    const int bid  = blockIdx.x;          // [0, 512)
    const int bh   = bid >> 5;
    const int t0   = (bid & 31) * 12;
    const int tid  = threadIdx.x;
    const int lane = tid & 63;
    const int wv   = __builtin_amdgcn_readfirstlane(tid >> 6); // 0..5
    const int r0   = 2 * wv;              // wave's local rows: r0, r0+1

    // initial staging: Ea tile (192 float4) + v_w (64 floats)
    if (tid < 192) {
        const float4* __restrict__ src = reinterpret_cast<const float4*>(
            (const float*)g_Ea4 + ((size_t)bh * NT + t0) * 64);
        reinterpret_cast<float4*>(eal)[tid] = src[tid];
    } else if (tid < 256) {
        vwl[tid - 192] = v_w[tid - 192];
    }
    __syncthreads();

    // C0 = sum(v_w) via butterfly (all lanes)
    float C0;
    {
        float s = vwl[lane];
#pragma unroll
        for (int o = 32; o > 0; o >>= 1) s += __shfl_xor(s, o, 64);
        C0 = s;
    }

    const float4* __restrict__ Ebg =
        reinterpret_cast<const float4*>((const float*)g_Eb4 + (size_t)bh * NS * 64);
    const float4* __restrict__ eal4 = reinterpret_cast<const float4*>(eal);
    const float4* __restrict__ vwl4 = reinterpret_cast<const float4*>(vwl);

    float p0[6], p1[6]; // this wave's 2 score rows, lane<->s within chunk

    // ---------------- Phase A: raw scores, chunk by chunk ----------------
#pragma unroll
    for (int sc = 0; sc < 6; ++sc) {
        __syncthreads(); // previous chunk's readers done
        {
            // stage Eb chunk sc: 1024 float4, coalesced, pitch 68
            int j = tid;
            {
                const float4 v = Ebg[sc * 1024 + j];
                *reinterpret_cast<float4*>(&ebl[(j >> 4) * 68 + (j & 15) * 4]) = v;
            }
            j += 384;
            {
                const float4 v = Ebg[sc * 1024 + j];
                *reinterpret_cast<float4*>(&ebl[(j >> 4) * 68 + (j & 15) * 4]) = v;
            }
            j += 384;
            if (j < 1024) {
                const float4 v = Ebg[sc * 1024 + j];
                *reinterpret_cast<float4*>(&ebl[(j >> 4) * 68 + (j & 15) * 4]) = v;
            }
        }
        __syncthreads();

        // hoist this lane's Eb row (s = sc*64 + lane) into 64 VGPRs
        float eb[64];
#pragma unroll
        for (int i = 0; i < 16; ++i) {
            const float4 v = *reinterpret_cast<const float4*>(&ebl[lane * 68 + i * 4]);
            eb[i * 4 + 0] = v.x; eb[i * 4 + 1] = v.y;
            eb[i * 4 + 2] = v.z; eb[i * 4 + 3] = v.w;
        }

        float a00 = 0.f, a01 = 0.f, a02 = 0.f, a03 = 0.f;
        float a10 = 0.f, a11 = 0.f, a12 = 0.f, a13 = 0.f;
#pragma unroll
        for (int e4 = 0; e4 < 16; ++e4) {
            const float4 Wv = vwl4[e4];                 // uniform broadcast
            const float4 A0 = eal4[r0 * 16 + e4];       // uniform broadcast
            const float4 A1 = eal4[r0 * 16 + 16 + e4];  // uniform broadcast
            a00 = fmaf(Wv.x, __builtin_amdgcn_rcpf(fmaf(A0.x, eb[e4 * 4 + 0], 1.f)), a00);
            a01 = fmaf(Wv.y, __builtin_amdgcn_rcpf(fmaf(A0.y, eb[e4 * 4 + 1], 1.f)), a01);
            a02 = fmaf(Wv.z, __builtin_amdgcn_rcpf(fmaf(A0.z, eb[e4 * 4 + 2], 1.f)), a02);
            a03 = fmaf(Wv.w, __builtin_amdgcn_rcpf(fmaf(A0.w, eb[e4 * 4 + 3], 1.f)), a03);
            a10 = fmaf(Wv.x, __builtin_amdgcn_rcpf(fmaf(A1.x, eb[e4 * 4 + 0], 1.f)), a10);
            a11 = fmaf(Wv.y, __builtin_amdgcn_rcpf(fmaf(A1.y, eb[e4 * 4 + 1], 1.f)), a11);
            a12 = fmaf(Wv.z, __builtin_amdgcn_rcpf(fmaf(A1.z, eb[e4 * 4 + 2], 1.f)), a12);
            a13 = fmaf(Wv.w, __builtin_amdgcn_rcpf(fmaf(A1.w, eb[e4 * 4 + 3], 1.f)), a13);
        }
        p0[sc] = C0 - 2.f * ((a00 + a01) + (a02 + a03));
        p1[sc] = C0 - 2.f * ((a10 + a11) + (a12 + a13));
    }

    // ---------------- Softmax (max-free; |score| < 24, exp2 safe) ----------
    {
        float tot0 = 0.f, tot1 = 0.f;
#pragma unroll
        for (int sc = 0; sc < 6; ++sc) {
            p0[sc] = __builtin_amdgcn_exp2f(p0[sc] * LOG2E);
            p1[sc] = __builtin_amdgcn_exp2f(p1[sc] * LOG2E);
            tot0 += p0[sc];
            tot1 += p1[sc];
        }
#pragma unroll
        for (int o = 32; o > 0; o >>= 1) {
            tot0 += __shfl_xor(tot0, o, 64);
            tot1 += __shfl_xor(tot1, o, 64);
        }
        const float i0 = __builtin_amdgcn_rcpf(tot0);
        const float i1 = __builtin_amdgcn_rcpf(tot1);
        float* __restrict__ a0p = attn + ((size_t)bh * NT + t0 + r0) * NS;
        float* __restrict__ a1p = a0p + NS;
#pragma unroll
        for (int sc = 0; sc < 6; ++sc) {
            p0[sc] *= i0;
            p1[sc] *= i1;
            a0p[sc * 64 + lane] = p0[sc];
            a1p[sc * 64 + lane] = p1[sc];
        }
    }

    // ---------------- PV: out[r][d] = sum_s P[r][s] V[s][d] ----------------
    const int g  = lane >> 4;        // s-subgroup 0..3
    const int dq = (lane & 15) * 4;  // d-quad
    float4 O0 = {0.f, 0.f, 0.f, 0.f};
    float4 O1 = {0.f, 0.f, 0.f, 0.f};
    const float4* __restrict__ Vg =
        reinterpret_cast<const float4*>(V + (size_t)bh * NS * 64);

#pragma unroll
    for (int sc = 0; sc < 6; ++sc) {
        __syncthreads(); // previous chunk consumed
        {
            int j = tid;
            {
                const float4 v = Vg[sc * 1024 + j];
                *reinterpret_cast<float4*>(&ebl[(j >> 4) * 68 + (j & 15) * 4]) = v;
            }
            j += 384;
            {
                const float4 v = Vg[sc * 1024 + j];
                *reinterpret_cast<float4*>(&ebl[(j >> 4) * 68 + (j & 15) * 4]) = v;
            }
            j += 384;
            if (j < 1024) {
                const float4 v = Vg[sc * 1024 + j];
                *reinterpret_cast<float4*>(&ebl[(j >> 4) * 68 + (j & 15) * 4]) = v;
            }
        }
        __syncthreads();

        const float q0c = p0[sc];
        const float q1c = p1[sc];
#pragma unroll
        for (int s4 = 0; s4 < 16; ++s4) {
            const int sl = s4 * 4 + g;
            const float4 v4 = *reinterpret_cast<const float4*>(&ebl[sl * 68 + dq]);
            const float q0 = __shfl(q0c, sl, 64);
            const float q1 = __shfl(q1c, sl, 64);
            O0.x = fmaf(q0, v4.x, O0.x); O0.y = fmaf(q0, v4.y, O0.y);
            O0.z = fmaf(q0, v4.z, O0.z); O0.w = fmaf(q0, v4.w, O0.w);
            O1.x = fmaf(q1, v4.x, O1.x); O1.y = fmaf(q1, v4.y, O1.y);
            O1.z = fmaf(q1, v4.z, O1.z); O1.w = fmaf(q1, v4.w, O1.w);
        }
    }

    // reduce partial O across the 4 s-subgroups (lane bits 4,5)
#pragma unroll
    for (int o = 16; o <= 32; o <<= 1) {
        O0.x += __shfl_xor(O0.x, o, 64); O0.y += __shfl_xor(O0.y, o, 64);
        O0.z += __shfl_xor(O0.z, o, 64); O0.w += __shfl_xor(O0.w, o, 64);
        O1.x += __shfl_xor(O1.x, o, 64); O1.y += __shfl_xor(O1.y, o, 64);
        O1.z += __shfl_xor(O1.z, o, 64); O1.w += __shfl_xor(O1.w, o, 64);
    }
    if (g == 0) {
        float* __restrict__ op = out + ((size_t)bh * NT + t0 + r0) * 64 + dq;
        *reinterpret_cast<float4*>(op)      = O0;
        *reinterpret_cast<float4*>(op + 64) = O1;
    }
}

extern "C" void kernel_launch(void* const* d_in, const int* in_sizes, int n_in,
                              void* d_out, int out_size, void* d_ws, size_t ws_size,
                              hipStream_t stream) {
    const float* q  = (const float*)d_in[0];
    const float* k  = (const float*)d_in[1];
    const float* v  = (const float*)d_in[2];
    const float* Wq = (const float*)d_in[3];
    const float* Wk = (const float*)d_in[4];
    const float* vw = (const float*)d_in[5];

    float* out  = (float*)d_out;              // (b,h,t,d) = 393216
    float* attn = out + (size_t)BH * NT * DD; // (b,h,t,s) = 2359296

    k1_proj <<<384, 256, 0, stream>>>(q, k, Wq, Wk);
    k2_fused<<<512, 384, 0, stream>>>(vw, v, out, attn);
}